// Round 1
// baseline (2871.716 us; speedup 1.0000x reference)
//
#include <hip/hip_runtime.h>
#include <math.h>

#define NE 8      // experts
#define ND 512    // features
#define NH 2048   // hidden
#define NT 2048   // tokens = B*S
#define TT 16     // token tile

// ---------------- gating ----------------
__global__ __launch_bounds__(256) void gate_kernel(
    const float* __restrict__ xr, const float* __restrict__ xi,
    const float* __restrict__ gW, const float* __restrict__ gb,
    int* __restrict__ expert_of, float* __restrict__ gate_w,
    int* __restrict__ counts, int* __restrict__ tok_list)
{
    int t = blockIdx.x;
    int tid = threadIdx.x;
    const float* xrt = xr + (size_t)t * ND;
    const float* xit = xi + (size_t)t * ND;

    float acc[NE] = {0,0,0,0,0,0,0,0};
    for (int r = tid; r < 2 * ND; r += 256) {
        int d = r & (ND - 1);
        float a = xrt[d], b = xit[d];
        float v = (r < ND) ? sqrtf(a * a + b * b) : atan2f(b, a);
        const float4* g = (const float4*)(gW + (size_t)r * NE);
        float4 g0 = g[0], g1 = g[1];
        acc[0] += v * g0.x; acc[1] += v * g0.y; acc[2] += v * g0.z; acc[3] += v * g0.w;
        acc[4] += v * g1.x; acc[5] += v * g1.y; acc[6] += v * g1.z; acc[7] += v * g1.w;
    }
    // wave reduce (64 lanes)
    #pragma unroll
    for (int e = 0; e < NE; e++) {
        for (int off = 32; off > 0; off >>= 1)
            acc[e] += __shfl_down(acc[e], off, 64);
    }
    __shared__ float part[4][NE];
    int wave = tid >> 6, lane = tid & 63;
    if (lane == 0) {
        #pragma unroll
        for (int e = 0; e < NE; e++) part[wave][e] = acc[e];
    }
    __syncthreads();
    if (tid == 0) {
        float s[NE];
        #pragma unroll
        for (int e = 0; e < NE; e++)
            s[e] = part[0][e] + part[1][e] + part[2][e] + part[3][e] + gb[e];
        int amax = 0; float m = s[0];
        #pragma unroll
        for (int e = 1; e < NE; e++) if (s[e] > m) { m = s[e]; amax = e; }
        float denom = 0.f;
        #pragma unroll
        for (int e = 0; e < NE; e++) denom += expf(s[e] - m);
        expert_of[t] = amax;
        gate_w[t] = 1.0f / denom;   // probs[argmax]
        int pos = atomicAdd(&counts[amax], 1);
        tok_list[amax * NT + pos] = t;
    }
}

// ---------------- stage 1: complex D->H + ModReLU ----------------
__global__ __launch_bounds__(256) void expert1_kernel(
    const float* __restrict__ xr, const float* __restrict__ xi,
    const float* __restrict__ W1r, const float* __restrict__ W1i,
    const float* __restrict__ b1r, const float* __restrict__ b1i,
    const float* __restrict__ mod_b,
    const int* __restrict__ counts, const int* __restrict__ tok_list,
    float* __restrict__ hws_r, float* __restrict__ hws_i)
{
    int e = blockIdx.y;
    int n = counts[e];
    if (n == 0) return;
    int h0 = blockIdx.x * 64;
    int strip = blockIdx.z;              // 0..3
    int tid = threadIdx.x;
    int hl = tid & 63;
    int tg = tid >> 6;                   // 0..3
    int h = h0 + hl;

    __shared__ float4 xs_r4[TT][32];     // 16 tok x 128 d
    __shared__ float4 xs_i4[TT][32];
    __shared__ int toks[TT];

    const float* W1r_e = W1r + (size_t)e * ND * NH;
    const float* W1i_e = W1i + (size_t)e * ND * NH;
    float br = b1r[(size_t)e * NH + h];
    float bi = b1i[(size_t)e * NH + h];
    float mb = mod_b[(size_t)e * NH + h];

    int nchunks = (n + TT - 1) / TT;
    for (int c = strip; c < nchunks; c += 4) {
        __syncthreads();                 // protect toks from prior-iter epilogue readers
        int base = c * TT;
        int nc = min(TT, n - base);
        if (tid < TT) toks[tid] = (tid < nc) ? tok_list[e * NT + base + tid] : -1;
        __syncthreads();

        float accr[4] = {0,0,0,0}, acci[4] = {0,0,0,0};
        for (int d0 = 0; d0 < ND; d0 += 128) {
            // load x tile (16 tok x 128 d, r+i) as float4
            for (int idx = tid; idx < TT * 32; idx += 256) {
                int tl = idx >> 5, d4 = idx & 31;
                int tok = toks[tl];
                float4 vr = make_float4(0.f,0.f,0.f,0.f);
                float4 vi = vr;
                if (tok >= 0) {
                    vr = *(const float4*)(xr + (size_t)tok * ND + d0 + d4 * 4);
                    vi = *(const float4*)(xi + (size_t)tok * ND + d0 + d4 * 4);
                }
                xs_r4[tl][d4] = vr;
                xs_i4[tl][d4] = vi;
            }
            __syncthreads();
            for (int d4 = 0; d4 < 32; ++d4) {
                size_t dbase = (size_t)(d0 + d4 * 4);
                float wr0 = W1r_e[(dbase + 0) * NH + h];
                float wr1 = W1r_e[(dbase + 1) * NH + h];
                float wr2 = W1r_e[(dbase + 2) * NH + h];
                float wr3 = W1r_e[(dbase + 3) * NH + h];
                float wi0 = W1i_e[(dbase + 0) * NH + h];
                float wi1 = W1i_e[(dbase + 1) * NH + h];
                float wi2 = W1i_e[(dbase + 2) * NH + h];
                float wi3 = W1i_e[(dbase + 3) * NH + h];
                #pragma unroll
                for (int j = 0; j < 4; ++j) {
                    int tl = tg + 4 * j;
                    float4 ar = xs_r4[tl][d4];
                    float4 ai = xs_i4[tl][d4];
                    accr[j] += ar.x * wr0 + ar.y * wr1 + ar.z * wr2 + ar.w * wr3
                             - ai.x * wi0 - ai.y * wi1 - ai.z * wi2 - ai.w * wi3;
                    acci[j] += ar.x * wi0 + ar.y * wi1 + ar.z * wi2 + ar.w * wi3
                             + ai.x * wr0 + ai.y * wr1 + ai.z * wr2 + ai.w * wr3;
                }
            }
            __syncthreads();
        }
        // epilogue: bias + ModReLU, store h
        #pragma unroll
        for (int j = 0; j < 4; ++j) {
            int tl = tg + 4 * j;
            int tok = toks[tl];
            if (tok < 0) continue;
            float vhr = accr[j] + br;
            float vhi = acci[j] + bi;
            float a = sqrtf(vhr * vhr + vhi * vhi + 1e-10f);
            float sc = fmaxf(a + mb, 0.0f) / (a + 1e-10f);
            hws_r[(size_t)tok * NH + h] = vhr * sc;
            hws_i[(size_t)tok * NH + h] = vhi * sc;
        }
    }
}

// ---------------- stage 2: complex H->D + gate scale + scatter ----------------
__global__ __launch_bounds__(256) void expert2_kernel(
    const float* __restrict__ hws_r, const float* __restrict__ hws_i,
    const float* __restrict__ W2r, const float* __restrict__ W2i,
    const float* __restrict__ b2r, const float* __restrict__ b2i,
    const int* __restrict__ counts, const int* __restrict__ tok_list,
    const float* __restrict__ gate_w,
    float* __restrict__ out)             // out_r at 0, out_i at NT*ND
{
    int e = blockIdx.y;
    int n = counts[e];
    if (n == 0) return;
    int d0 = blockIdx.x * 64;            // 8 tiles over D
    int strip = blockIdx.z;              // 0..7
    int tid = threadIdx.x;
    int dl = tid & 63;
    int tg = tid >> 6;
    int d = d0 + dl;

    __shared__ float4 hs_r4[TT][32];     // 16 tok x 128 k
    __shared__ float4 hs_i4[TT][32];
    __shared__ int toks[TT];

    const float* W2r_e = W2r + (size_t)e * NH * ND;
    const float* W2i_e = W2i + (size_t)e * NH * ND;
    float br = b2r[(size_t)e * ND + d];
    float bi = b2i[(size_t)e * ND + d];

    int nchunks = (n + TT - 1) / TT;
    for (int c = strip; c < nchunks; c += 8) {
        __syncthreads();
        int base = c * TT;
        int nc = min(TT, n - base);
        if (tid < TT) toks[tid] = (tid < nc) ? tok_list[e * NT + base + tid] : -1;
        __syncthreads();

        float accr[4] = {0,0,0,0}, acci[4] = {0,0,0,0};
        for (int k0 = 0; k0 < NH; k0 += 128) {
            for (int idx = tid; idx < TT * 32; idx += 256) {
                int tl = idx >> 5, k4 = idx & 31;
                int tok = toks[tl];
                float4 vr = make_float4(0.f,0.f,0.f,0.f);
                float4 vi = vr;
                if (tok >= 0) {
                    vr = *(const float4*)(hws_r + (size_t)tok * NH + k0 + k4 * 4);
                    vi = *(const float4*)(hws_i + (size_t)tok * NH + k0 + k4 * 4);
                }
                hs_r4[tl][k4] = vr;
                hs_i4[tl][k4] = vi;
            }
            __syncthreads();
            for (int k4 = 0; k4 < 32; ++k4) {
                size_t kb = (size_t)(k0 + k4 * 4);
                float wr0 = W2r_e[(kb + 0) * ND + d];
                float wr1 = W2r_e[(kb + 1) * ND + d];
                float wr2 = W2r_e[(kb + 2) * ND + d];
                float wr3 = W2r_e[(kb + 3) * ND + d];
                float wi0 = W2i_e[(kb + 0) * ND + d];
                float wi1 = W2i_e[(kb + 1) * ND + d];
                float wi2 = W2i_e[(kb + 2) * ND + d];
                float wi3 = W2i_e[(kb + 3) * ND + d];
                #pragma unroll
                for (int j = 0; j < 4; ++j) {
                    int tl = tg + 4 * j;
                    float4 ar = hs_r4[tl][k4];
                    float4 ai = hs_i4[tl][k4];
                    accr[j] += ar.x * wr0 + ar.y * wr1 + ar.z * wr2 + ar.w * wr3
                             - ai.x * wi0 - ai.y * wi1 - ai.z * wi2 - ai.w * wi3;
                    acci[j] += ar.x * wi0 + ar.y * wi1 + ar.z * wi2 + ar.w * wi3
                             + ai.x * wr0 + ai.y * wr1 + ai.z * wr2 + ai.w * wr3;
                }
            }
            __syncthreads();
        }
        #pragma unroll
        for (int j = 0; j < 4; ++j) {
            int tl = tg + 4 * j;
            int tok = toks[tl];
            if (tok < 0) continue;
            float w = gate_w[tok];
            out[(size_t)tok * ND + d]                    = (accr[j] + br) * w;
            out[(size_t)NT * ND + (size_t)tok * ND + d]  = (acci[j] + bi) * w;
        }
    }
}

extern "C" void kernel_launch(void* const* d_in, const int* in_sizes, int n_in,
                              void* d_out, int out_size, void* d_ws, size_t ws_size,
                              hipStream_t stream) {
    const float* xr   = (const float*)d_in[0];
    const float* xi   = (const float*)d_in[1];
    const float* gW   = (const float*)d_in[2];
    const float* gb   = (const float*)d_in[3];
    const float* W1r  = (const float*)d_in[4];
    const float* W1i  = (const float*)d_in[5];
    const float* b1r  = (const float*)d_in[6];
    const float* b1i  = (const float*)d_in[7];
    const float* modb = (const float*)d_in[8];
    const float* W2r  = (const float*)d_in[9];
    const float* W2i  = (const float*)d_in[10];
    const float* b2r  = (const float*)d_in[11];
    const float* b2i  = (const float*)d_in[12];
    float* out = (float*)d_out;

    // workspace layout (4-byte words)
    int*   wsi       = (int*)d_ws;
    float* wsf       = (float*)d_ws;
    int*   counts    = wsi;                       // 64 words
    int*   expert_of = wsi + 64;                  // NT
    float* gate_w    = wsf + 64 + NT;             // NT
    int*   tok_list  = wsi + 64 + 2 * NT;         // NE*NT
    float* h_r       = wsf + 64 + 2 * NT + NE * NT;
    float* h_i       = h_r + (size_t)NT * NH;

    hipMemsetAsync(counts, 0, 64 * sizeof(int), stream);
    gate_kernel<<<NT, 256, 0, stream>>>(xr, xi, gW, gb, expert_of, gate_w, counts, tok_list);
    expert1_kernel<<<dim3(NH / 64, NE, 4), 256, 0, stream>>>(
        xr, xi, W1r, W1i, b1r, b1i, modb, counts, tok_list, h_r, h_i);
    expert2_kernel<<<dim3(ND / 64, NE, 8), 256, 0, stream>>>(
        h_r, h_i, W2r, W2i, b2r, b2i, counts, tok_list, gate_w, out);
}

// Round 2
// 660.329 us; speedup vs baseline: 4.3489x; 4.3489x over previous
//
#include <hip/hip_runtime.h>
#include <math.h>

#define NE 8      // experts
#define ND 512    // features
#define NH 2048   // hidden
#define NT 2048   // tokens = B*S

typedef __attribute__((ext_vector_type(8))) short short8;   // 8 bf16 = 4 VGPRs
typedef __attribute__((ext_vector_type(4))) float f32x4;    // MFMA accumulator

__device__ __forceinline__ unsigned short f2bf(float x) {
    unsigned int u = __builtin_bit_cast(unsigned int, x);
    u += 0x7FFFu + ((u >> 16) & 1u);            // round-to-nearest-even
    return (unsigned short)(u >> 16);
}

__device__ __forceinline__ short8 neg8(short8 v) {
    int4 u = __builtin_bit_cast(int4, v);
    u.x ^= 0x80008000; u.y ^= 0x80008000; u.z ^= 0x80008000; u.w ^= 0x80008000;
    return __builtin_bit_cast(short8, u);
}

__device__ __forceinline__ short8 ld8(const unsigned short* p) {
    return *(const short8*)p;
}

// ---------------- gating (fp32, exact argmax semantics) ----------------
__global__ __launch_bounds__(256) void gate_kernel(
    const float* __restrict__ xr, const float* __restrict__ xi,
    const float* __restrict__ gW, const float* __restrict__ gb,
    float* __restrict__ gate_w,
    int* __restrict__ counts, int* __restrict__ tok_list)
{
    int t = blockIdx.x;
    int tid = threadIdx.x;
    const float* xrt = xr + (size_t)t * ND;
    const float* xit = xi + (size_t)t * ND;

    float acc[NE] = {0,0,0,0,0,0,0,0};
    for (int r = tid; r < 2 * ND; r += 256) {
        int d = r & (ND - 1);
        float a = xrt[d], b = xit[d];
        float v = (r < ND) ? sqrtf(a * a + b * b) : atan2f(b, a);
        const float4* g = (const float4*)(gW + (size_t)r * NE);
        float4 g0 = g[0], g1 = g[1];
        acc[0] += v * g0.x; acc[1] += v * g0.y; acc[2] += v * g0.z; acc[3] += v * g0.w;
        acc[4] += v * g1.x; acc[5] += v * g1.y; acc[6] += v * g1.z; acc[7] += v * g1.w;
    }
    #pragma unroll
    for (int e = 0; e < NE; e++) {
        for (int off = 32; off > 0; off >>= 1)
            acc[e] += __shfl_down(acc[e], off, 64);
    }
    __shared__ float part[4][NE];
    int wave = tid >> 6, lane = tid & 63;
    if (lane == 0) {
        #pragma unroll
        for (int e = 0; e < NE; e++) part[wave][e] = acc[e];
    }
    __syncthreads();
    if (tid == 0) {
        float s[NE];
        #pragma unroll
        for (int e = 0; e < NE; e++)
            s[e] = part[0][e] + part[1][e] + part[2][e] + part[3][e] + gb[e];
        int amax = 0; float m = s[0];
        #pragma unroll
        for (int e = 1; e < NE; e++) if (s[e] > m) { m = s[e]; amax = e; }
        float denom = 0.f;
        #pragma unroll
        for (int e = 0; e < NE; e++) denom += expf(s[e] - m);
        gate_w[t] = 1.0f / denom;
        int pos = atomicAdd(&counts[amax], 1);
        tok_list[amax * NT + pos] = t;
    }
}

// ---------------- x -> bf16 ----------------
__global__ __launch_bounds__(256) void convx_kernel(
    const float* __restrict__ xr, const float* __restrict__ xi,
    unsigned short* __restrict__ obr, unsigned short* __restrict__ obi)
{
    int i = blockIdx.x * 256 + threadIdx.x;       // NT*ND/4 = 262144 threads
    float4 vr = ((const float4*)xr)[i];
    float4 vi = ((const float4*)xi)[i];
    ushort4 pr = make_ushort4(f2bf(vr.x), f2bf(vr.y), f2bf(vr.z), f2bf(vr.w));
    ushort4 pi = make_ushort4(f2bf(vi.x), f2bf(vi.y), f2bf(vi.z), f2bf(vi.w));
    ((ushort4*)obr)[i] = pr;
    ((ushort4*)obi)[i] = pi;
}

// ---------------- weight transpose + bf16: src fp32 [e][R][C] -> dst bf16 [e][C][R] ----
__global__ __launch_bounds__(256) void transw_kernel(
    const float* __restrict__ s0, unsigned short* __restrict__ d0,
    const float* __restrict__ s1, unsigned short* __restrict__ d1,
    int R, int C)
{
    __shared__ float tile[64][65];
    int e = blockIdx.z;
    int c0 = blockIdx.x * 64, r0 = blockIdx.y * 64;
    size_t off = (size_t)e * R * C;
    int tid = threadIdx.x;
    #pragma unroll
    for (int p = 0; p < 2; ++p) {
        const float* src = (p ? s1 : s0) + off;
        unsigned short* dst = (p ? d1 : d0) + off;
        if (p) __syncthreads();
        for (int i = 0; i < 16; ++i) {
            int idx = tid + i * 256;
            int r = idx >> 6, c = idx & 63;
            tile[r][c] = src[(size_t)(r0 + r) * C + c0 + c];
        }
        __syncthreads();
        for (int i = 0; i < 16; ++i) {
            int idx = tid + i * 256;
            int c = idx >> 6, r = idx & 63;
            dst[(size_t)(c0 + c) * R + r0 + r] = f2bf(tile[r][c]);
        }
    }
}

// ---------------- stage 1: complex D->H MFMA + ModReLU -> h bf16 ----------------
// wave tile: M=16 tokens, N=64 (4 subtiles); block = 4 waves -> N=256
__global__ __launch_bounds__(256) void moe1_kernel(
    const unsigned short* __restrict__ xbr, const unsigned short* __restrict__ xbi,
    const unsigned short* __restrict__ w1tr, const unsigned short* __restrict__ w1ti,
    const float* __restrict__ b1r, const float* __restrict__ b1i,
    const float* __restrict__ mod_b,
    const int* __restrict__ counts, const int* __restrict__ tok_list,
    unsigned short* __restrict__ hr, unsigned short* __restrict__ hi)
{
    int e = blockIdx.y;
    int n = counts[e];
    if (n == 0) return;
    int tid = threadIdx.x;
    int wave = tid >> 6, lane = tid & 63;
    int l15 = lane & 15, quad = lane >> 4;
    int n0 = blockIdx.x * 256 + wave * 64;
    const int* tl = tok_list + e * NT;
    int nchunks = (n + 15) >> 4;

    for (int c = blockIdx.z; c < nchunks; c += 16) {
        int base = c * 16;
        int ti = base + l15;
        int tokA = tl[ti < n ? ti : 0];
        const unsigned short* par = xbr + (size_t)tokA * ND + quad * 8;
        const unsigned short* pai = xbi + (size_t)tokA * ND + quad * 8;
        const unsigned short* pbr[4];
        const unsigned short* pbi[4];
        #pragma unroll
        for (int s = 0; s < 4; ++s) {
            size_t row = (size_t)e * NH + n0 + s * 16 + l15;
            pbr[s] = w1tr + row * ND + quad * 8;
            pbi[s] = w1ti + row * ND + quad * 8;
        }
        f32x4 accr[4] = {}, acci[4] = {};
        #pragma unroll 2
        for (int k0 = 0; k0 < ND; k0 += 32) {
            short8 ar = ld8(par + k0);
            short8 ai = ld8(pai + k0);
            short8 an = neg8(ai);
            #pragma unroll
            for (int s = 0; s < 4; ++s) {
                short8 br = ld8(pbr[s] + k0);
                short8 bi = ld8(pbi[s] + k0);
                accr[s] = __builtin_amdgcn_mfma_f32_16x16x32_bf16(ar, br, accr[s], 0, 0, 0);
                acci[s] = __builtin_amdgcn_mfma_f32_16x16x32_bf16(ar, bi, acci[s], 0, 0, 0);
                accr[s] = __builtin_amdgcn_mfma_f32_16x16x32_bf16(an, bi, accr[s], 0, 0, 0);
                acci[s] = __builtin_amdgcn_mfma_f32_16x16x32_bf16(ai, br, acci[s], 0, 0, 0);
            }
        }
        // epilogue: C/D layout col = lane&15, row = quad*4 + r
        #pragma unroll
        for (int r = 0; r < 4; ++r) {
            int ti2 = base + quad * 4 + r;
            if (ti2 >= n) continue;
            int tok = tl[ti2];
            #pragma unroll
            for (int s = 0; s < 4; ++s) {
                int col = n0 + s * 16 + l15;
                float vr = accr[s][r] + b1r[(size_t)e * NH + col];
                float vi = acci[s][r] + b1i[(size_t)e * NH + col];
                float a = sqrtf(vr * vr + vi * vi + 1e-10f);
                float sc = fmaxf(a + mod_b[(size_t)e * NH + col], 0.0f) / (a + 1e-10f);
                hr[(size_t)tok * NH + col] = f2bf(vr * sc);
                hi[(size_t)tok * NH + col] = f2bf(vi * sc);
            }
        }
    }
}

// ---------------- stage 2: complex H->D MFMA + gate scale -> out fp32 ----------------
// wave tile: M=16 tokens, N=32 (2 subtiles); block = 4 waves -> N=128
__global__ __launch_bounds__(256) void moe2_kernel(
    const unsigned short* __restrict__ hr, const unsigned short* __restrict__ hi,
    const unsigned short* __restrict__ w2tr, const unsigned short* __restrict__ w2ti,
    const float* __restrict__ b2r, const float* __restrict__ b2i,
    const int* __restrict__ counts, const int* __restrict__ tok_list,
    const float* __restrict__ gate_w,
    float* __restrict__ out)
{
    int e = blockIdx.y;
    int n = counts[e];
    if (n == 0) return;
    int tid = threadIdx.x;
    int wave = tid >> 6, lane = tid & 63;
    int l15 = lane & 15, quad = lane >> 4;
    int n0 = blockIdx.x * 128 + wave * 32;
    const int* tl = tok_list + e * NT;
    int nchunks = (n + 15) >> 4;

    for (int c = blockIdx.z; c < nchunks; c += 16) {
        int base = c * 16;
        int ti = base + l15;
        int tokA = tl[ti < n ? ti : 0];
        const unsigned short* par = hr + (size_t)tokA * NH + quad * 8;
        const unsigned short* pai = hi + (size_t)tokA * NH + quad * 8;
        const unsigned short* pbr[2];
        const unsigned short* pbi[2];
        #pragma unroll
        for (int s = 0; s < 2; ++s) {
            size_t row = (size_t)e * ND + n0 + s * 16 + l15;
            pbr[s] = w2tr + row * NH + quad * 8;
            pbi[s] = w2ti + row * NH + quad * 8;
        }
        f32x4 accr[2] = {}, acci[2] = {};
        #pragma unroll 2
        for (int k0 = 0; k0 < NH; k0 += 32) {
            short8 ar = ld8(par + k0);
            short8 ai = ld8(pai + k0);
            short8 an = neg8(ai);
            #pragma unroll
            for (int s = 0; s < 2; ++s) {
                short8 br = ld8(pbr[s] + k0);
                short8 bi = ld8(pbi[s] + k0);
                accr[s] = __builtin_amdgcn_mfma_f32_16x16x32_bf16(ar, br, accr[s], 0, 0, 0);
                acci[s] = __builtin_amdgcn_mfma_f32_16x16x32_bf16(ar, bi, acci[s], 0, 0, 0);
                accr[s] = __builtin_amdgcn_mfma_f32_16x16x32_bf16(an, bi, accr[s], 0, 0, 0);
                acci[s] = __builtin_amdgcn_mfma_f32_16x16x32_bf16(ai, br, acci[s], 0, 0, 0);
            }
        }
        #pragma unroll
        for (int r = 0; r < 4; ++r) {
            int ti2 = base + quad * 4 + r;
            if (ti2 >= n) continue;
            int tok = tl[ti2];
            float w = gate_w[tok];
            #pragma unroll
            for (int s = 0; s < 2; ++s) {
                int col = n0 + s * 16 + l15;
                out[(size_t)tok * ND + col] =
                    (accr[s][r] + b2r[(size_t)e * ND + col]) * w;
                out[(size_t)NT * ND + (size_t)tok * ND + col] =
                    (acci[s][r] + b2i[(size_t)e * ND + col]) * w;
            }
        }
    }
}

extern "C" void kernel_launch(void* const* d_in, const int* in_sizes, int n_in,
                              void* d_out, int out_size, void* d_ws, size_t ws_size,
                              hipStream_t stream) {
    const float* xr   = (const float*)d_in[0];
    const float* xi   = (const float*)d_in[1];
    const float* gW   = (const float*)d_in[2];
    const float* gb   = (const float*)d_in[3];
    const float* W1r  = (const float*)d_in[4];
    const float* W1i  = (const float*)d_in[5];
    const float* b1r  = (const float*)d_in[6];
    const float* b1i  = (const float*)d_in[7];
    const float* modb = (const float*)d_in[8];
    const float* W2r  = (const float*)d_in[9];
    const float* W2i  = (const float*)d_in[10];
    const float* b2r  = (const float*)d_in[11];
    const float* b2i  = (const float*)d_in[12];
    float* out = (float*)d_out;

    // ---- workspace layout (bytes), all sections 16B-aligned ----
    char* ws = (char*)d_ws;
    int*   counts   = (int*)ws;                              // 256 B
    float* gate_w   = (float*)(ws + 256);                    // NT*4 = 8 KB
    int*   tok_list = (int*)(ws + 256 + 8192);               // NE*NT*4 = 64 KB
    size_t off = 256 + 8192 + (size_t)NE * NT * 4;           // 73984
    unsigned short* xbr  = (unsigned short*)(ws + off); off += (size_t)NT * ND * 2;
    unsigned short* xbi  = (unsigned short*)(ws + off); off += (size_t)NT * ND * 2;
    unsigned short* w1tr = (unsigned short*)(ws + off); off += (size_t)NE * ND * NH * 2;
    unsigned short* w1ti = (unsigned short*)(ws + off); off += (size_t)NE * ND * NH * 2;
    unsigned short* w2tr = (unsigned short*)(ws + off); off += (size_t)NE * ND * NH * 2;
    unsigned short* w2ti = (unsigned short*)(ws + off); off += (size_t)NE * ND * NH * 2;
    unsigned short* h_r  = (unsigned short*)(ws + off); off += (size_t)NT * NH * 2;
    unsigned short* h_i  = (unsigned short*)(ws + off); off += (size_t)NT * NH * 2;

    hipMemsetAsync(counts, 0, 64 * sizeof(int), stream);
    gate_kernel<<<NT, 256, 0, stream>>>(xr, xi, gW, gb, gate_w, counts, tok_list);
    convx_kernel<<<(NT * ND / 4) / 256, 256, 0, stream>>>(xr, xi, xbr, xbi);
    // W1 [e][D][H] -> w1t [e][H][D]
    transw_kernel<<<dim3(NH / 64, ND / 64, NE), 256, 0, stream>>>(W1r, w1tr, W1i, w1ti, ND, NH);
    // W2 [e][H][D] -> w2t [e][D][H]
    transw_kernel<<<dim3(ND / 64, NH / 64, NE), 256, 0, stream>>>(W2r, w2tr, W2i, w2ti, NH, ND);
    moe1_kernel<<<dim3(NH / 256, NE, 16), 256, 0, stream>>>(
        xbr, xbi, w1tr, w1ti, b1r, b1i, modb, counts, tok_list, h_r, h_i);
    moe2_kernel<<<dim3(ND / 128, NE, 16), 256, 0, stream>>>(
        h_r, h_i, w2tr, w2ti, b2r, b2i, counts, tok_list, gate_w, out);
}

// Round 3
// 350.361 us; speedup vs baseline: 8.1964x; 1.8847x over previous
//
#include <hip/hip_runtime.h>
#include <math.h>

#define NE 8      // experts
#define ND 512    // features
#define NH 2048   // hidden
#define NT 2048   // tokens = B*S

typedef __attribute__((ext_vector_type(8))) short short8;   // 8 bf16 = 4 VGPRs
typedef __attribute__((ext_vector_type(4))) float f32x4;    // MFMA accumulator

#define GLL(g, d) __builtin_amdgcn_global_load_lds( \
    (const __attribute__((address_space(1))) void*)(g), \
    (__attribute__((address_space(3))) void*)(d), 16, 0, 0)

__device__ __forceinline__ unsigned short f2bf(float x) {
    unsigned int u = __builtin_bit_cast(unsigned int, x);
    u += 0x7FFFu + ((u >> 16) & 1u);            // round-to-nearest-even
    return (unsigned short)(u >> 16);
}

__device__ __forceinline__ short8 neg8(short8 v) {
    int4 u = __builtin_bit_cast(int4, v);
    u.x ^= 0x80008000; u.y ^= 0x80008000; u.z ^= 0x80008000; u.w ^= 0x80008000;
    return __builtin_bit_cast(short8, u);
}

__device__ __forceinline__ short8 lds8(const unsigned short* p) {
    return *(const short8*)p;
}

// ---------------- gating (fp32, exact argmax semantics) ----------------
__global__ __launch_bounds__(256) void gate_kernel(
    const float* __restrict__ xr, const float* __restrict__ xi,
    const float* __restrict__ gW, const float* __restrict__ gb,
    float* __restrict__ gate_w,
    int* __restrict__ counts, int* __restrict__ tok_list)
{
    int t = blockIdx.x;
    int tid = threadIdx.x;
    const float* xrt = xr + (size_t)t * ND;
    const float* xit = xi + (size_t)t * ND;

    float acc[NE] = {0,0,0,0,0,0,0,0};
    for (int r = tid; r < 2 * ND; r += 256) {
        int d = r & (ND - 1);
        float a = xrt[d], b = xit[d];
        float v = (r < ND) ? sqrtf(a * a + b * b) : atan2f(b, a);
        const float4* g = (const float4*)(gW + (size_t)r * NE);
        float4 g0 = g[0], g1 = g[1];
        acc[0] += v * g0.x; acc[1] += v * g0.y; acc[2] += v * g0.z; acc[3] += v * g0.w;
        acc[4] += v * g1.x; acc[5] += v * g1.y; acc[6] += v * g1.z; acc[7] += v * g1.w;
    }
    #pragma unroll
    for (int e = 0; e < NE; e++) {
        for (int off = 32; off > 0; off >>= 1)
            acc[e] += __shfl_down(acc[e], off, 64);
    }
    __shared__ float part[4][NE];
    int wave = tid >> 6, lane = tid & 63;
    if (lane == 0) {
        #pragma unroll
        for (int e = 0; e < NE; e++) part[wave][e] = acc[e];
    }
    __syncthreads();
    if (tid == 0) {
        float s[NE];
        #pragma unroll
        for (int e = 0; e < NE; e++)
            s[e] = part[0][e] + part[1][e] + part[2][e] + part[3][e] + gb[e];
        int amax = 0; float m = s[0];
        #pragma unroll
        for (int e = 1; e < NE; e++) if (s[e] > m) { m = s[e]; amax = e; }
        float denom = 0.f;
        #pragma unroll
        for (int e = 0; e < NE; e++) denom += expf(s[e] - m);
        gate_w[t] = 1.0f / denom;
        int pos = atomicAdd(&counts[amax], 1);
        tok_list[amax * NT + pos] = t;
    }
}

// ---------------- x -> bf16 ----------------
__global__ __launch_bounds__(256) void convx_kernel(
    const float* __restrict__ xr, const float* __restrict__ xi,
    unsigned short* __restrict__ obr, unsigned short* __restrict__ obi)
{
    int i = blockIdx.x * 256 + threadIdx.x;
    float4 vr = ((const float4*)xr)[i];
    float4 vi = ((const float4*)xi)[i];
    ((ushort4*)obr)[i] = make_ushort4(f2bf(vr.x), f2bf(vr.y), f2bf(vr.z), f2bf(vr.w));
    ((ushort4*)obi)[i] = make_ushort4(f2bf(vi.x), f2bf(vi.y), f2bf(vi.z), f2bf(vi.w));
}

// ---------------- weight transpose + bf16: src fp32 [e][R][C] -> dst bf16 [e][C][R] ----
__global__ __launch_bounds__(256) void transw_kernel(
    const float* __restrict__ s0, unsigned short* __restrict__ d0,
    const float* __restrict__ s1, unsigned short* __restrict__ d1,
    int R, int C)
{
    __shared__ float tile[64][65];
    int e = blockIdx.z;
    int c0 = blockIdx.x * 64, r0 = blockIdx.y * 64;
    size_t off = (size_t)e * R * C;
    int tid = threadIdx.x;
    #pragma unroll
    for (int p = 0; p < 2; ++p) {
        const float* src = (p ? s1 : s0) + off;
        unsigned short* dst = (p ? d1 : d0) + off;
        if (p) __syncthreads();
        for (int i = 0; i < 16; ++i) {
            int idx = tid + i * 256;
            int r = idx >> 6, c = idx & 63;
            tile[r][c] = src[(size_t)(r0 + r) * C + c0 + c];
        }
        __syncthreads();
        for (int i = 0; i < 16; ++i) {
            int idx = tid + i * 256;
            int c = idx >> 6, r = idx & 63;
            dst[(size_t)(c0 + c) * R + r0 + r] = f2bf(tile[r][c]);
        }
    }
}

// ---------------- stage 1: complex D->H, LDS-tiled MFMA + ModReLU -> h bf16 ---
// block tile: 64 tokens x 128 cols, BK=64; 4 waves, wave = 64M x 32N
__global__ __launch_bounds__(256) void moe1_kernel(
    const unsigned short* __restrict__ xbr, const unsigned short* __restrict__ xbi,
    const unsigned short* __restrict__ w1tr, const unsigned short* __restrict__ w1ti,
    const float* __restrict__ b1r, const float* __restrict__ b1i,
    const float* __restrict__ mod_b,
    const int* __restrict__ counts, const int* __restrict__ tok_list,
    unsigned short* __restrict__ hr, unsigned short* __restrict__ hi)
{
    int e = blockIdx.z;
    int n = counts[e];
    int mbase = blockIdx.y * 64;
    if (mbase >= n) return;
    int n0 = blockIdx.x * 128;
    int tid = threadIdx.x;
    int w = tid >> 6, l = tid & 63;
    int l15 = l & 15, quad = l >> 4;

    __shared__ unsigned short sAr[64 * 64];   // 8 KB
    __shared__ unsigned short sAi[64 * 64];
    __shared__ unsigned short sBr[128 * 64];  // 16 KB
    __shared__ unsigned short sBi[128 * 64];
    __shared__ int toks[64];

    const int* tl = tok_list + e * NT;
    if (tid < 64) {
        int idx = mbase + tid;
        toks[tid] = tl[idx < n ? idx : n - 1];
    }
    __syncthreads();

    int lk = (l & 7) * 8;                       // element offset within row chunk
    int ra0 = toks[w * 16 + (l >> 3)];
    int ra1 = toks[w * 16 + 8 + (l >> 3)];
    const unsigned short* gAr0 = xbr + (size_t)ra0 * ND + lk;
    const unsigned short* gAi0 = xbi + (size_t)ra0 * ND + lk;
    const unsigned short* gAr1 = xbr + (size_t)ra1 * ND + lk;
    const unsigned short* gAi1 = xbi + (size_t)ra1 * ND + lk;
    size_t brow = (size_t)e * NH + n0 + w * 32 + (l >> 3);
    const unsigned short* gBr0 = w1tr + (brow +  0) * ND + lk;
    const unsigned short* gBr1 = w1tr + (brow +  8) * ND + lk;
    const unsigned short* gBr2 = w1tr + (brow + 16) * ND + lk;
    const unsigned short* gBr3 = w1tr + (brow + 24) * ND + lk;
    const unsigned short* gBi0 = w1ti + (brow +  0) * ND + lk;
    const unsigned short* gBi1 = w1ti + (brow +  8) * ND + lk;
    const unsigned short* gBi2 = w1ti + (brow + 16) * ND + lk;
    const unsigned short* gBi3 = w1ti + (brow + 24) * ND + lk;

    unsigned short* dAr0 = sAr + (w * 16) * 64;
    unsigned short* dAr1 = sAr + (w * 16 + 8) * 64;
    unsigned short* dAi0 = sAi + (w * 16) * 64;
    unsigned short* dAi1 = sAi + (w * 16 + 8) * 64;
    unsigned short* dBr0 = sBr + (w * 32) * 64;
    unsigned short* dBr1 = sBr + (w * 32 + 8) * 64;
    unsigned short* dBr2 = sBr + (w * 32 + 16) * 64;
    unsigned short* dBr3 = sBr + (w * 32 + 24) * 64;
    unsigned short* dBi0 = sBi + (w * 32) * 64;
    unsigned short* dBi1 = sBi + (w * 32 + 8) * 64;
    unsigned short* dBi2 = sBi + (w * 32 + 16) * 64;
    unsigned short* dBi3 = sBi + (w * 32 + 24) * 64;

    f32x4 accr[4][2] = {}, acci[4][2] = {};

    for (int kt = 0; kt < ND / 64; ++kt) {
        __syncthreads();                         // previous tile's reads done
        int ko = kt * 64;
        GLL(gAr0 + ko, dAr0); GLL(gAi0 + ko, dAi0);
        GLL(gAr1 + ko, dAr1); GLL(gAi1 + ko, dAi1);
        GLL(gBr0 + ko, dBr0); GLL(gBr1 + ko, dBr1);
        GLL(gBr2 + ko, dBr2); GLL(gBr3 + ko, dBr3);
        GLL(gBi0 + ko, dBi0); GLL(gBi1 + ko, dBi1);
        GLL(gBi2 + ko, dBi2); GLL(gBi3 + ko, dBi3);
        __syncthreads();                         // vmcnt(0) drain + barrier
        #pragma unroll
        for (int ks = 0; ks < 2; ++ks) {
            int kb = ks * 32 + quad * 8;
            short8 ar[4], ai2[4], an[4];
            #pragma unroll
            for (int m = 0; m < 4; ++m) {
                ar[m]  = lds8(sAr + (m * 16 + l15) * 64 + kb);
                ai2[m] = lds8(sAi + (m * 16 + l15) * 64 + kb);
                an[m]  = neg8(ai2[m]);
            }
            short8 br[2], bi2[2];
            #pragma unroll
            for (int t = 0; t < 2; ++t) {
                br[t]  = lds8(sBr + (w * 32 + t * 16 + l15) * 64 + kb);
                bi2[t] = lds8(sBi + (w * 32 + t * 16 + l15) * 64 + kb);
            }
            #pragma unroll
            for (int m = 0; m < 4; ++m)
                #pragma unroll
                for (int t = 0; t < 2; ++t) {
                    accr[m][t] = __builtin_amdgcn_mfma_f32_16x16x32_bf16(ar[m],  br[t],  accr[m][t], 0, 0, 0);
                    accr[m][t] = __builtin_amdgcn_mfma_f32_16x16x32_bf16(an[m],  bi2[t], accr[m][t], 0, 0, 0);
                    acci[m][t] = __builtin_amdgcn_mfma_f32_16x16x32_bf16(ar[m],  bi2[t], acci[m][t], 0, 0, 0);
                    acci[m][t] = __builtin_amdgcn_mfma_f32_16x16x32_bf16(ai2[m], br[t],  acci[m][t], 0, 0, 0);
                }
        }
    }

    // epilogue: C/D layout col = lane&15 (N), row = quad*4 + r (M)
    #pragma unroll
    for (int t = 0; t < 2; ++t) {
        int col = n0 + w * 32 + t * 16 + l15;
        float bre = b1r[(size_t)e * NH + col];
        float bie = b1i[(size_t)e * NH + col];
        float mbv = mod_b[(size_t)e * NH + col];
        #pragma unroll
        for (int m = 0; m < 4; ++m) {
            #pragma unroll
            for (int r = 0; r < 4; ++r) {
                int tix = m * 16 + quad * 4 + r;
                if (mbase + tix >= n) continue;
                int tok = toks[tix];
                float vr = accr[m][t][r] + bre;
                float vi = acci[m][t][r] + bie;
                float a = sqrtf(vr * vr + vi * vi + 1e-10f);
                float sc = fmaxf(a + mbv, 0.0f) / (a + 1e-10f);
                hr[(size_t)tok * NH + col] = f2bf(vr * sc);
                hi[(size_t)tok * NH + col] = f2bf(vi * sc);
            }
        }
    }
}

// ---------------- stage 2: complex H->D, LDS-tiled MFMA + gate -> out fp32 ----
// block tile: 64 tokens x 64 cols, BK=64; 4 waves, wave = 64M x 16N
__global__ __launch_bounds__(256) void moe2_kernel(
    const unsigned short* __restrict__ hr, const unsigned short* __restrict__ hi,
    const unsigned short* __restrict__ w2tr, const unsigned short* __restrict__ w2ti,
    const float* __restrict__ b2r, const float* __restrict__ b2i,
    const int* __restrict__ counts, const int* __restrict__ tok_list,
    const float* __restrict__ gate_w,
    float* __restrict__ out)
{
    int e = blockIdx.z;
    int n = counts[e];
    int mbase = blockIdx.y * 64;
    if (mbase >= n) return;
    int n0 = blockIdx.x * 64;
    int tid = threadIdx.x;
    int w = tid >> 6, l = tid & 63;
    int l15 = l & 15, quad = l >> 4;

    __shared__ unsigned short sAr[64 * 64];
    __shared__ unsigned short sAi[64 * 64];
    __shared__ unsigned short sBr[64 * 64];
    __shared__ unsigned short sBi[64 * 64];
    __shared__ int toks[64];

    const int* tl = tok_list + e * NT;
    if (tid < 64) {
        int idx = mbase + tid;
        toks[tid] = tl[idx < n ? idx : n - 1];
    }
    __syncthreads();

    int lk = (l & 7) * 8;
    int ra0 = toks[w * 16 + (l >> 3)];
    int ra1 = toks[w * 16 + 8 + (l >> 3)];
    const unsigned short* gAr0 = hr + (size_t)ra0 * NH + lk;
    const unsigned short* gAi0 = hi + (size_t)ra0 * NH + lk;
    const unsigned short* gAr1 = hr + (size_t)ra1 * NH + lk;
    const unsigned short* gAi1 = hi + (size_t)ra1 * NH + lk;
    size_t brow = (size_t)e * ND + n0 + w * 16 + (l >> 3);
    const unsigned short* gBr0 = w2tr + (brow + 0) * NH + lk;
    const unsigned short* gBr1 = w2tr + (brow + 8) * NH + lk;
    const unsigned short* gBi0 = w2ti + (brow + 0) * NH + lk;
    const unsigned short* gBi1 = w2ti + (brow + 8) * NH + lk;

    unsigned short* dAr0 = sAr + (w * 16) * 64;
    unsigned short* dAr1 = sAr + (w * 16 + 8) * 64;
    unsigned short* dAi0 = sAi + (w * 16) * 64;
    unsigned short* dAi1 = sAi + (w * 16 + 8) * 64;
    unsigned short* dBr0 = sBr + (w * 16) * 64;
    unsigned short* dBr1 = sBr + (w * 16 + 8) * 64;
    unsigned short* dBi0 = sBi + (w * 16) * 64;
    unsigned short* dBi1 = sBi + (w * 16 + 8) * 64;

    f32x4 accr[4] = {}, acci[4] = {};

    for (int kt = 0; kt < NH / 64; ++kt) {
        __syncthreads();
        int ko = kt * 64;
        GLL(gAr0 + ko, dAr0); GLL(gAi0 + ko, dAi0);
        GLL(gAr1 + ko, dAr1); GLL(gAi1 + ko, dAi1);
        GLL(gBr0 + ko, dBr0); GLL(gBr1 + ko, dBr1);
        GLL(gBi0 + ko, dBi0); GLL(gBi1 + ko, dBi1);
        __syncthreads();
        #pragma unroll
        for (int ks = 0; ks < 2; ++ks) {
            int kb = ks * 32 + quad * 8;
            short8 br = lds8(sBr + (w * 16 + l15) * 64 + kb);
            short8 bi2 = lds8(sBi + (w * 16 + l15) * 64 + kb);
            #pragma unroll
            for (int m = 0; m < 4; ++m) {
                short8 ar  = lds8(sAr + (m * 16 + l15) * 64 + kb);
                short8 ai2 = lds8(sAi + (m * 16 + l15) * 64 + kb);
                short8 an  = neg8(ai2);
                accr[m] = __builtin_amdgcn_mfma_f32_16x16x32_bf16(ar,  br,  accr[m], 0, 0, 0);
                accr[m] = __builtin_amdgcn_mfma_f32_16x16x32_bf16(an,  bi2, accr[m], 0, 0, 0);
                acci[m] = __builtin_amdgcn_mfma_f32_16x16x32_bf16(ar,  bi2, acci[m], 0, 0, 0);
                acci[m] = __builtin_amdgcn_mfma_f32_16x16x32_bf16(ai2, br,  acci[m], 0, 0, 0);
            }
        }
    }

    int col = n0 + w * 16 + l15;
    float bre = b2r[(size_t)e * ND + col];
    float bie = b2i[(size_t)e * ND + col];
    #pragma unroll
    for (int m = 0; m < 4; ++m) {
        #pragma unroll
        for (int r = 0; r < 4; ++r) {
            int tix = m * 16 + quad * 4 + r;
            if (mbase + tix >= n) continue;
            int tok = toks[tix];
            float gw = gate_w[tok];
            out[(size_t)tok * ND + col] = (accr[m][r] + bre) * gw;
            out[(size_t)NT * ND + (size_t)tok * ND + col] = (acci[m][r] + bie) * gw;
        }
    }
}

extern "C" void kernel_launch(void* const* d_in, const int* in_sizes, int n_in,
                              void* d_out, int out_size, void* d_ws, size_t ws_size,
                              hipStream_t stream) {
    const float* xr   = (const float*)d_in[0];
    const float* xi   = (const float*)d_in[1];
    const float* gW   = (const float*)d_in[2];
    const float* gb   = (const float*)d_in[3];
    const float* W1r  = (const float*)d_in[4];
    const float* W1i  = (const float*)d_in[5];
    const float* b1r  = (const float*)d_in[6];
    const float* b1i  = (const float*)d_in[7];
    const float* modb = (const float*)d_in[8];
    const float* W2r  = (const float*)d_in[9];
    const float* W2i  = (const float*)d_in[10];
    const float* b2r  = (const float*)d_in[11];
    const float* b2i  = (const float*)d_in[12];
    float* out = (float*)d_out;

    char* ws = (char*)d_ws;
    int*   counts   = (int*)ws;                              // 256 B
    float* gate_w   = (float*)(ws + 256);                    // NT*4
    int*   tok_list = (int*)(ws + 256 + 8192);               // NE*NT*4
    size_t off = 256 + 8192 + (size_t)NE * NT * 4;
    unsigned short* xbr  = (unsigned short*)(ws + off); off += (size_t)NT * ND * 2;
    unsigned short* xbi  = (unsigned short*)(ws + off); off += (size_t)NT * ND * 2;
    unsigned short* w1tr = (unsigned short*)(ws + off); off += (size_t)NE * ND * NH * 2;
    unsigned short* w1ti = (unsigned short*)(ws + off); off += (size_t)NE * ND * NH * 2;
    unsigned short* w2tr = (unsigned short*)(ws + off); off += (size_t)NE * ND * NH * 2;
    unsigned short* w2ti = (unsigned short*)(ws + off); off += (size_t)NE * ND * NH * 2;
    unsigned short* h_r  = (unsigned short*)(ws + off); off += (size_t)NT * NH * 2;
    unsigned short* h_i  = (unsigned short*)(ws + off); off += (size_t)NT * NH * 2;

    hipMemsetAsync(counts, 0, 64 * sizeof(int), stream);
    gate_kernel<<<NT, 256, 0, stream>>>(xr, xi, gW, gb, gate_w, counts, tok_list);
    convx_kernel<<<(NT * ND / 4) / 256, 256, 0, stream>>>(xr, xi, xbr, xbi);
    transw_kernel<<<dim3(NH / 64, ND / 64, NE), 256, 0, stream>>>(W1r, w1tr, W1i, w1ti, ND, NH);
    transw_kernel<<<dim3(ND / 64, NH / 64, NE), 256, 0, stream>>>(W2r, w2tr, W2i, w2ti, NH, ND);
    moe1_kernel<<<dim3(NH / 128, NT / 64, NE), 256, 0, stream>>>(
        xbr, xbi, w1tr, w1ti, b1r, b1i, modb, counts, tok_list, h_r, h_i);
    moe2_kernel<<<dim3(ND / 64, NT / 64, NE), 256, 0, stream>>>(
        h_r, h_i, w2tr, w2ti, b2r, b2i, counts, tok_list, gate_w, out);
}

// Round 4
// 314.134 us; speedup vs baseline: 9.1417x; 1.1153x over previous
//
#include <hip/hip_runtime.h>
#include <math.h>

#define NE 8      // experts
#define ND 512    // features
#define NH 2048   // hidden
#define NT 2048   // tokens = B*S

typedef __attribute__((ext_vector_type(8))) short short8;   // 8 bf16 = 4 VGPRs
typedef __attribute__((ext_vector_type(4))) float f32x4;    // MFMA accumulator

#define GLL(g, d) __builtin_amdgcn_global_load_lds( \
    (const __attribute__((address_space(1))) void*)(g), \
    (__attribute__((address_space(3))) void*)(d), 16, 0, 0)

__device__ __forceinline__ unsigned short f2bf(float x) {
    unsigned int u = __builtin_bit_cast(unsigned int, x);
    u += 0x7FFFu + ((u >> 16) & 1u);            // round-to-nearest-even
    return (unsigned short)(u >> 16);
}

__device__ __forceinline__ short8 neg8(short8 v) {
    int4 u = __builtin_bit_cast(int4, v);
    u.x ^= 0x80008000; u.y ^= 0x80008000; u.z ^= 0x80008000; u.w ^= 0x80008000;
    return __builtin_bit_cast(short8, u);
}

__device__ __forceinline__ short8 lds8(const unsigned short* p) {
    return *(const short8*)p;
}

// ---------------- gating (fp32, exact argmax semantics) ----------------
__global__ __launch_bounds__(256) void gate_kernel(
    const float* __restrict__ xr, const float* __restrict__ xi,
    const float* __restrict__ gW, const float* __restrict__ gb,
    float* __restrict__ gate_w,
    int* __restrict__ counts, int* __restrict__ tok_list)
{
    int t = blockIdx.x;
    int tid = threadIdx.x;
    const float* xrt = xr + (size_t)t * ND;
    const float* xit = xi + (size_t)t * ND;

    float acc[NE] = {0,0,0,0,0,0,0,0};
    for (int r = tid; r < 2 * ND; r += 256) {
        int d = r & (ND - 1);
        float a = xrt[d], b = xit[d];
        float v = (r < ND) ? sqrtf(a * a + b * b) : atan2f(b, a);
        const float4* g = (const float4*)(gW + (size_t)r * NE);
        float4 g0 = g[0], g1 = g[1];
        acc[0] += v * g0.x; acc[1] += v * g0.y; acc[2] += v * g0.z; acc[3] += v * g0.w;
        acc[4] += v * g1.x; acc[5] += v * g1.y; acc[6] += v * g1.z; acc[7] += v * g1.w;
    }
    #pragma unroll
    for (int e = 0; e < NE; e++) {
        for (int off = 32; off > 0; off >>= 1)
            acc[e] += __shfl_down(acc[e], off, 64);
    }
    __shared__ float part[4][NE];
    int wave = tid >> 6, lane = tid & 63;
    if (lane == 0) {
        #pragma unroll
        for (int e = 0; e < NE; e++) part[wave][e] = acc[e];
    }
    __syncthreads();
    if (tid == 0) {
        float s[NE];
        #pragma unroll
        for (int e = 0; e < NE; e++)
            s[e] = part[0][e] + part[1][e] + part[2][e] + part[3][e] + gb[e];
        int amax = 0; float m = s[0];
        #pragma unroll
        for (int e = 1; e < NE; e++) if (s[e] > m) { m = s[e]; amax = e; }
        float denom = 0.f;
        #pragma unroll
        for (int e = 0; e < NE; e++) denom += expf(s[e] - m);
        gate_w[t] = 1.0f / denom;
        int pos = atomicAdd(&counts[amax], 1);
        tok_list[amax * NT + pos] = t;
    }
}

// ---------------- x -> bf16 ----------------
__global__ __launch_bounds__(256) void convx_kernel(
    const float* __restrict__ xr, const float* __restrict__ xi,
    unsigned short* __restrict__ obr, unsigned short* __restrict__ obi)
{
    int i = blockIdx.x * 256 + threadIdx.x;
    float4 vr = ((const float4*)xr)[i];
    float4 vi = ((const float4*)xi)[i];
    ((ushort4*)obr)[i] = make_ushort4(f2bf(vr.x), f2bf(vr.y), f2bf(vr.z), f2bf(vr.w));
    ((ushort4*)obi)[i] = make_ushort4(f2bf(vi.x), f2bf(vi.y), f2bf(vi.z), f2bf(vi.w));
}

// ---------------- weight transpose + bf16: src fp32 [e][R][C] -> dst bf16 [e][C][R] ----
__global__ __launch_bounds__(256) void transw_kernel(
    const float* __restrict__ s0, unsigned short* __restrict__ d0,
    const float* __restrict__ s1, unsigned short* __restrict__ d1,
    int R, int C)
{
    __shared__ float tile[64][65];
    int e = blockIdx.z;
    int c0 = blockIdx.x * 64, r0 = blockIdx.y * 64;
    size_t off = (size_t)e * R * C;
    int tid = threadIdx.x;
    #pragma unroll
    for (int p = 0; p < 2; ++p) {
        const float* src = (p ? s1 : s0) + off;
        unsigned short* dst = (p ? d1 : d0) + off;
        if (p) __syncthreads();
        for (int i = 0; i < 16; ++i) {
            int idx = tid + i * 256;
            int r = idx >> 6, c = idx & 63;
            tile[r][c] = src[(size_t)(r0 + r) * C + c0 + c];
        }
        __syncthreads();
        for (int i = 0; i < 16; ++i) {
            int idx = tid + i * 256;
            int c = idx >> 6, r = idx & 63;
            dst[(size_t)(c0 + c) * R + r0 + r] = f2bf(tile[r][c]);
        }
    }
}

// ---------------- stage 1: complex D->H, LDS-tiled MFMA + ModReLU -> h bf16 ---
// block tile: 64 tokens x 64 cols, BK=64; 4 waves, wave = 64M x 16N
// LDS XOR swizzle: physical k-chunk = logical ^ (row & 7); applied on the
// global-source side of GLL (LDS slot order is fixed to lane order).
__global__ __launch_bounds__(256, 4) void moe1_kernel(
    const unsigned short* __restrict__ xbr, const unsigned short* __restrict__ xbi,
    const unsigned short* __restrict__ w1tr, const unsigned short* __restrict__ w1ti,
    const float* __restrict__ b1r, const float* __restrict__ b1i,
    const float* __restrict__ mod_b,
    const int* __restrict__ counts, const int* __restrict__ tok_list,
    unsigned short* __restrict__ hr, unsigned short* __restrict__ hi)
{
    int e = blockIdx.z;
    int n = counts[e];
    int mbase = blockIdx.y * 64;
    if (mbase >= n) return;
    int n0 = blockIdx.x * 64;
    int tid = threadIdx.x;
    int w = tid >> 6, l = tid & 63;
    int l15 = l & 15, quad = l >> 4;

    __shared__ unsigned short sAr[64 * 64];   // 8 KB each
    __shared__ unsigned short sAi[64 * 64];
    __shared__ unsigned short sBr[64 * 64];
    __shared__ unsigned short sBi[64 * 64];
    __shared__ int toks[64];

    const int* tl = tok_list + e * NT;
    if (tid < 64) {
        int idx = mbase + tid;
        toks[tid] = tl[idx < n ? idx : n - 1];
    }
    __syncthreads();

    int swz = (((l & 7) ^ ((l >> 3) & 7)) * 8);   // swizzled element offset in row
    int ra0 = toks[w * 16 + (l >> 3)];
    int ra1 = toks[w * 16 + 8 + (l >> 3)];
    const unsigned short* gAr0 = xbr + (size_t)ra0 * ND + swz;
    const unsigned short* gAi0 = xbi + (size_t)ra0 * ND + swz;
    const unsigned short* gAr1 = xbr + (size_t)ra1 * ND + swz;
    const unsigned short* gAi1 = xbi + (size_t)ra1 * ND + swz;
    size_t brow = (size_t)e * NH + n0 + w * 16 + (l >> 3);
    const unsigned short* gBr0 = w1tr + brow * ND + swz;
    const unsigned short* gBr1 = w1tr + (brow + 8) * ND + swz;
    const unsigned short* gBi0 = w1ti + brow * ND + swz;
    const unsigned short* gBi1 = w1ti + (brow + 8) * ND + swz;

    unsigned short* dAr0 = sAr + (w * 16) * 64;
    unsigned short* dAr1 = sAr + (w * 16 + 8) * 64;
    unsigned short* dAi0 = sAi + (w * 16) * 64;
    unsigned short* dAi1 = sAi + (w * 16 + 8) * 64;
    unsigned short* dBr0 = sBr + (w * 16) * 64;
    unsigned short* dBr1 = sBr + (w * 16 + 8) * 64;
    unsigned short* dBi0 = sBi + (w * 16) * 64;
    unsigned short* dBi1 = sBi + (w * 16 + 8) * 64;

    f32x4 accr[4] = {}, acci[4] = {};

    for (int kt = 0; kt < ND / 64; ++kt) {
        __syncthreads();
        int ko = kt * 64;
        GLL(gAr0 + ko, dAr0); GLL(gAi0 + ko, dAi0);
        GLL(gAr1 + ko, dAr1); GLL(gAi1 + ko, dAi1);
        GLL(gBr0 + ko, dBr0); GLL(gBr1 + ko, dBr1);
        GLL(gBi0 + ko, dBi0); GLL(gBi1 + ko, dBi1);
        __syncthreads();
        #pragma unroll
        for (int ks = 0; ks < 2; ++ks) {
            int pa = ((ks * 4 + quad) ^ (l15 & 7)) * 8;   // unswizzled read offset
            short8 br  = lds8(sBr + (w * 16 + l15) * 64 + pa);
            short8 bi2 = lds8(sBi + (w * 16 + l15) * 64 + pa);
            #pragma unroll
            for (int m = 0; m < 4; ++m) {
                short8 ar  = lds8(sAr + (m * 16 + l15) * 64 + pa);
                short8 ai2 = lds8(sAi + (m * 16 + l15) * 64 + pa);
                short8 an  = neg8(ai2);
                accr[m] = __builtin_amdgcn_mfma_f32_16x16x32_bf16(ar,  br,  accr[m], 0, 0, 0);
                accr[m] = __builtin_amdgcn_mfma_f32_16x16x32_bf16(an,  bi2, accr[m], 0, 0, 0);
                acci[m] = __builtin_amdgcn_mfma_f32_16x16x32_bf16(ar,  bi2, acci[m], 0, 0, 0);
                acci[m] = __builtin_amdgcn_mfma_f32_16x16x32_bf16(ai2, br,  acci[m], 0, 0, 0);
            }
        }
    }

    // epilogue: C/D layout col = lane&15 (N), row = quad*4 + r (M)
    int col = n0 + w * 16 + l15;
    float bre = b1r[(size_t)e * NH + col];
    float bie = b1i[(size_t)e * NH + col];
    float mbv = mod_b[(size_t)e * NH + col];
    #pragma unroll
    for (int m = 0; m < 4; ++m) {
        #pragma unroll
        for (int r = 0; r < 4; ++r) {
            int tix = m * 16 + quad * 4 + r;
            if (mbase + tix >= n) continue;
            int tok = toks[tix];
            float vr = accr[m][r] + bre;
            float vi = acci[m][r] + bie;
            float a = sqrtf(vr * vr + vi * vi + 1e-10f);
            float sc = fmaxf(a + mbv, 0.0f) / (a + 1e-10f);
            hr[(size_t)tok * NH + col] = f2bf(vr * sc);
            hi[(size_t)tok * NH + col] = f2bf(vi * sc);
        }
    }
}

// ---------------- stage 2: complex H->D, split-K=4, LDS-tiled MFMA -> atomic out
// block tile: 64 tokens x 64 cols, K-slice 512, BK=64; 4 waves, wave = 64M x 16N
__global__ __launch_bounds__(256, 4) void moe2_kernel(
    const unsigned short* __restrict__ hr, const unsigned short* __restrict__ hi,
    const unsigned short* __restrict__ w2tr, const unsigned short* __restrict__ w2ti,
    const float* __restrict__ b2r, const float* __restrict__ b2i,
    const int* __restrict__ counts, const int* __restrict__ tok_list,
    const float* __restrict__ gate_w,
    float* __restrict__ out)
{
    int e = blockIdx.z >> 2;
    int ksl = blockIdx.z & 3;
    int n = counts[e];
    int mbase = blockIdx.y * 64;
    if (mbase >= n) return;
    int n0 = blockIdx.x * 64;
    int kbase = ksl * (NH / 4);
    int tid = threadIdx.x;
    int w = tid >> 6, l = tid & 63;
    int l15 = l & 15, quad = l >> 4;

    __shared__ unsigned short sAr[64 * 64];
    __shared__ unsigned short sAi[64 * 64];
    __shared__ unsigned short sBr[64 * 64];
    __shared__ unsigned short sBi[64 * 64];
    __shared__ int toks[64];

    const int* tl = tok_list + e * NT;
    if (tid < 64) {
        int idx = mbase + tid;
        toks[tid] = tl[idx < n ? idx : n - 1];
    }
    __syncthreads();

    int swz = (((l & 7) ^ ((l >> 3) & 7)) * 8);
    int ra0 = toks[w * 16 + (l >> 3)];
    int ra1 = toks[w * 16 + 8 + (l >> 3)];
    const unsigned short* gAr0 = hr + (size_t)ra0 * NH + kbase + swz;
    const unsigned short* gAi0 = hi + (size_t)ra0 * NH + kbase + swz;
    const unsigned short* gAr1 = hr + (size_t)ra1 * NH + kbase + swz;
    const unsigned short* gAi1 = hi + (size_t)ra1 * NH + kbase + swz;
    size_t brow = (size_t)e * ND + n0 + w * 16 + (l >> 3);
    const unsigned short* gBr0 = w2tr + brow * NH + kbase + swz;
    const unsigned short* gBr1 = w2tr + (brow + 8) * NH + kbase + swz;
    const unsigned short* gBi0 = w2ti + brow * NH + kbase + swz;
    const unsigned short* gBi1 = w2ti + (brow + 8) * NH + kbase + swz;

    unsigned short* dAr0 = sAr + (w * 16) * 64;
    unsigned short* dAr1 = sAr + (w * 16 + 8) * 64;
    unsigned short* dAi0 = sAi + (w * 16) * 64;
    unsigned short* dAi1 = sAi + (w * 16 + 8) * 64;
    unsigned short* dBr0 = sBr + (w * 16) * 64;
    unsigned short* dBr1 = sBr + (w * 16 + 8) * 64;
    unsigned short* dBi0 = sBi + (w * 16) * 64;
    unsigned short* dBi1 = sBi + (w * 16 + 8) * 64;

    f32x4 accr[4] = {}, acci[4] = {};

    for (int kt = 0; kt < (NH / 4) / 64; ++kt) {
        __syncthreads();
        int ko = kt * 64;
        GLL(gAr0 + ko, dAr0); GLL(gAi0 + ko, dAi0);
        GLL(gAr1 + ko, dAr1); GLL(gAi1 + ko, dAi1);
        GLL(gBr0 + ko, dBr0); GLL(gBr1 + ko, dBr1);
        GLL(gBi0 + ko, dBi0); GLL(gBi1 + ko, dBi1);
        __syncthreads();
        #pragma unroll
        for (int ks = 0; ks < 2; ++ks) {
            int pa = ((ks * 4 + quad) ^ (l15 & 7)) * 8;
            short8 br  = lds8(sBr + (w * 16 + l15) * 64 + pa);
            short8 bi2 = lds8(sBi + (w * 16 + l15) * 64 + pa);
            #pragma unroll
            for (int m = 0; m < 4; ++m) {
                short8 ar  = lds8(sAr + (m * 16 + l15) * 64 + pa);
                short8 ai2 = lds8(sAi + (m * 16 + l15) * 64 + pa);
                short8 an  = neg8(ai2);
                accr[m] = __builtin_amdgcn_mfma_f32_16x16x32_bf16(ar,  br,  accr[m], 0, 0, 0);
                accr[m] = __builtin_amdgcn_mfma_f32_16x16x32_bf16(an,  bi2, accr[m], 0, 0, 0);
                acci[m] = __builtin_amdgcn_mfma_f32_16x16x32_bf16(ar,  bi2, acci[m], 0, 0, 0);
                acci[m] = __builtin_amdgcn_mfma_f32_16x16x32_bf16(ai2, br,  acci[m], 0, 0, 0);
            }
        }
    }

    int col = n0 + w * 16 + l15;
    float bre = (ksl == 0) ? b2r[(size_t)e * ND + col] : 0.0f;
    float bie = (ksl == 0) ? b2i[(size_t)e * ND + col] : 0.0f;
    #pragma unroll
    for (int m = 0; m < 4; ++m) {
        #pragma unroll
        for (int r = 0; r < 4; ++r) {
            int tix = m * 16 + quad * 4 + r;
            if (mbase + tix >= n) continue;
            int tok = toks[tix];
            float gw = gate_w[tok];
            atomicAdd(&out[(size_t)tok * ND + col], (accr[m][r] + bre) * gw);
            atomicAdd(&out[(size_t)NT * ND + (size_t)tok * ND + col], (acci[m][r] + bie) * gw);
        }
    }
}

extern "C" void kernel_launch(void* const* d_in, const int* in_sizes, int n_in,
                              void* d_out, int out_size, void* d_ws, size_t ws_size,
                              hipStream_t stream) {
    const float* xr   = (const float*)d_in[0];
    const float* xi   = (const float*)d_in[1];
    const float* gW   = (const float*)d_in[2];
    const float* gb   = (const float*)d_in[3];
    const float* W1r  = (const float*)d_in[4];
    const float* W1i  = (const float*)d_in[5];
    const float* b1r  = (const float*)d_in[6];
    const float* b1i  = (const float*)d_in[7];
    const float* modb = (const float*)d_in[8];
    const float* W2r  = (const float*)d_in[9];
    const float* W2i  = (const float*)d_in[10];
    const float* b2r  = (const float*)d_in[11];
    const float* b2i  = (const float*)d_in[12];
    float* out = (float*)d_out;

    char* ws = (char*)d_ws;
    int*   counts   = (int*)ws;                              // 256 B
    float* gate_w   = (float*)(ws + 256);                    // NT*4
    int*   tok_list = (int*)(ws + 256 + 8192);               // NE*NT*4
    size_t off = 256 + 8192 + (size_t)NE * NT * 4;
    unsigned short* xbr  = (unsigned short*)(ws + off); off += (size_t)NT * ND * 2;
    unsigned short* xbi  = (unsigned short*)(ws + off); off += (size_t)NT * ND * 2;
    unsigned short* w1tr = (unsigned short*)(ws + off); off += (size_t)NE * ND * NH * 2;
    unsigned short* w1ti = (unsigned short*)(ws + off); off += (size_t)NE * ND * NH * 2;
    unsigned short* w2tr = (unsigned short*)(ws + off); off += (size_t)NE * ND * NH * 2;
    unsigned short* w2ti = (unsigned short*)(ws + off); off += (size_t)NE * ND * NH * 2;
    unsigned short* h_r  = (unsigned short*)(ws + off); off += (size_t)NT * NH * 2;
    unsigned short* h_i  = (unsigned short*)(ws + off); off += (size_t)NT * NH * 2;

    hipMemsetAsync(counts, 0, 64 * sizeof(int), stream);
    hipMemsetAsync(out, 0, (size_t)out_size * sizeof(float), stream);
    gate_kernel<<<NT, 256, 0, stream>>>(xr, xi, gW, gb, gate_w, counts, tok_list);
    convx_kernel<<<(NT * ND / 4) / 256, 256, 0, stream>>>(xr, xi, xbr, xbi);
    transw_kernel<<<dim3(NH / 64, ND / 64, NE), 256, 0, stream>>>(W1r, w1tr, W1i, w1ti, ND, NH);
    transw_kernel<<<dim3(ND / 64, NH / 64, NE), 256, 0, stream>>>(W2r, w2tr, W2i, w2ti, NH, ND);
    moe1_kernel<<<dim3(NH / 64, NT / 64, NE), 256, 0, stream>>>(
        xbr, xbi, w1tr, w1ti, b1r, b1i, modb, counts, tok_list, h_r, h_i);
    moe2_kernel<<<dim3(ND / 64, NT / 64, NE * 4), 256, 0, stream>>>(
        h_r, h_i, w2tr, w2ti, b2r, b2i, counts, tok_list, gate_w, out);
}